// Round 1
// baseline (405.625 us; speedup 1.0000x reference)
//
#include <hip/hip_runtime.h>
#include <hip/hip_bf16.h>

typedef __attribute__((ext_vector_type(4))) float  f32x4;
typedef __attribute__((ext_vector_type(8))) short  bf16x8;
typedef __attribute__((ext_vector_type(4))) unsigned u32x4;

#define ME 128            // edges per block
#define NEG_SLOPE 0.01f

__device__ __forceinline__ unsigned short f2bf(float f) {
    unsigned u = __builtin_bit_cast(unsigned, f);
    return (unsigned short)((u + 0x7FFFu + ((u >> 16) & 1u)) >> 16);  // RNE
}
__device__ __forceinline__ unsigned pack2(float a, float b) {
    return (unsigned)f2bf(a) | ((unsigned)f2bf(b) << 16);
}

// One block: ME=128 edges x 128 output cols. 4 waves, wave w owns cols [32w, 32w+32).
// A-tile: [128 rows][256 k] bf16 in LDS, XOR-swizzled (byte ^= (row&7)<<4).
// B (W_edge^T) held as per-wave register fragments (2 n-tiles x 8 k-tiles).
__global__ __launch_bounds__(256, 2)
void gat_edge_kernel(const float* __restrict__ n_f,
                     const int*   __restrict__ src_idx,
                     const int*   __restrict__ dst_idx,
                     const float* __restrict__ W_edge,   // [128][256] row-major (o, i)
                     const float* __restrict__ W_attn,   // [128]
                     float* __restrict__ e_out,          // [E][128]
                     float* __restrict__ a_out,          // [E]
                     int E)
{
    __shared__ short Atile[ME * 256];   // 64 KB, swizzled
    __shared__ float a_acc[ME];

    const int tid  = threadIdx.x;
    const int lane = tid & 63;
    const int wave = tid >> 6;
    const int edge_base = blockIdx.x * ME;

    if (tid < ME) a_acc[tid] = 0.0f;

    // ---- gather: 256 (edge,half) rows; 16 rows/iter, 16 lanes per row (32B/lane)
    #pragma unroll
    for (int it = 0; it < 16; ++it) {
        int pair = it * 16 + (tid >> 4);   // 0..255
        int e  = pair >> 1;                // row within tile
        int hf = pair & 1;                 // 0 = src half, 1 = dst half
        int q  = tid & 15;                 // 8-float chunk within the 128-wide row
        int ge = edge_base + e;
        int idx = (ge < E) ? (hf ? dst_idx[ge] : src_idx[ge]) : 0;
        const float* p = n_f + (size_t)idx * 128 + q * 8;
        f32x4 v0 = *(const f32x4*)p;
        f32x4 v1 = *(const f32x4*)(p + 4);
        u32x4 u;
        u.x = pack2(v0.x, v0.y);
        u.y = pack2(v0.z, v0.w);
        u.z = pack2(v1.x, v1.y);
        u.w = pack2(v1.z, v1.w);
        int byteoff = (e * 512 + hf * 256 + q * 16) ^ ((e & 7) << 4);
        *(u32x4*)((char*)Atile + byteoff) = u;
    }

    // ---- B fragments: lane l holds B[k0+ (l>>4)*8 + j][n0 + nt*16 + (l&15)]
    //      = W_edge[n][k...k+8] (contiguous f32 in W_edge row)
    const int bn = lane & 15;
    const int bk = (lane >> 4) * 8;
    const int n0 = wave * 32;
    bf16x8 bfrag[2][8];
    #pragma unroll
    for (int nt = 0; nt < 2; ++nt) {
        #pragma unroll
        for (int kt = 0; kt < 8; ++kt) {
            const float* wp = W_edge + (size_t)(n0 + nt * 16 + bn) * 256 + kt * 32 + bk;
            f32x4 w0 = *(const f32x4*)wp;
            f32x4 w1 = *(const f32x4*)(wp + 4);
            bf16x8 f;
            f[0] = (short)f2bf(w0.x); f[1] = (short)f2bf(w0.y);
            f[2] = (short)f2bf(w0.z); f[3] = (short)f2bf(w0.w);
            f[4] = (short)f2bf(w1.x); f[5] = (short)f2bf(w1.y);
            f[6] = (short)f2bf(w1.z); f[7] = (short)f2bf(w1.w);
            bfrag[nt][kt] = f;
        }
    }
    const float wa0 = W_attn[n0 + bn];
    const float wa1 = W_attn[n0 + 16 + bn];

    __syncthreads();

    // ---- MFMA main loop: 8 row-tiles of 16 rows; each wave does 2 n-tiles
    const int a_koff = (lane >> 4) * 16;   // byte offset of this lane's 8-elem k-chunk
    #pragma unroll
    for (int rt = 0; rt < 8; ++rt) {
        const int row = rt * 16 + (lane & 15);
        f32x4 acc0 = {0.f, 0.f, 0.f, 0.f};
        f32x4 acc1 = {0.f, 0.f, 0.f, 0.f};
        #pragma unroll
        for (int kt = 0; kt < 8; ++kt) {
            int byteoff = (row * 512 + kt * 64 + a_koff) ^ ((row & 7) << 4);
            bf16x8 afrag = *(const bf16x8*)((const char*)Atile + byteoff);
            acc0 = __builtin_amdgcn_mfma_f32_16x16x32_bf16(afrag, bfrag[0][kt], acc0, 0, 0, 0);
            acc1 = __builtin_amdgcn_mfma_f32_16x16x32_bf16(afrag, bfrag[1][kt], acc1, 0, 0, 0);
        }
        // epilogue: C layout col = lane&15, row = (lane>>4)*4 + j
        const int crow = rt * 16 + (lane >> 4) * 4;
        #pragma unroll
        for (int j = 0; j < 4; ++j) {
            int r  = crow + j;
            int ge = edge_base + r;
            float c0 = fmaxf(acc0[j], 0.f);
            float c1 = fmaxf(acc1[j], 0.f);
            if (ge < E) {
                e_out[(size_t)ge * 128 + n0 + bn]      = c0;
                e_out[(size_t)ge * 128 + n0 + 16 + bn] = c1;
            }
            float pdot = c0 * wa0 + c1 * wa1;
            pdot += __shfl_xor(pdot, 1);
            pdot += __shfl_xor(pdot, 2);
            pdot += __shfl_xor(pdot, 4);
            pdot += __shfl_xor(pdot, 8);
            if (bn == 0) atomicAdd(&a_acc[r], pdot);
        }
    }

    __syncthreads();
    if (tid < ME) {
        int ge = edge_base + tid;
        if (ge < E) {
            float a = a_acc[tid];
            a_out[ge] = (a > 0.f) ? a : NEG_SLOPE * a;
        }
    }
}

extern "C" void kernel_launch(void* const* d_in, const int* in_sizes, int n_in,
                              void* d_out, int out_size, void* d_ws, size_t ws_size,
                              hipStream_t stream) {
    const float* n_f     = (const float*)d_in[0];
    const int*   src_idx = (const int*)d_in[1];
    const int*   dst_idx = (const int*)d_in[2];
    const float* W_edge  = (const float*)d_in[3];
    const float* W_attn  = (const float*)d_in[4];
    const int E = in_sizes[1];

    float* e_out = (float*)d_out;
    float* a_out = e_out + (size_t)E * 128;

    int nblocks = (E + ME - 1) / ME;
    gat_edge_kernel<<<nblocks, 256, 0, stream>>>(n_f, src_idx, dst_idx, W_edge, W_attn,
                                                 e_out, a_out, E);
}